// Round 8
// baseline (609.305 us; speedup 1.0000x reference)
//
#include <hip/hip_runtime.h>

#define BB 128
#define TT 2048
#define II 32
#define HH 64

// ws layout: float xh[2][BB][HH][TT]   (xw written by proj, overwritten in-place by h in rnn)
// total = 2*128*64*2048*4 = 128 MiB

__global__ __launch_bounds__(256) void proj_kernel(
    const float* __restrict__ x,
    const float* __restrict__ Wf, const float* __restrict__ bihf, const float* __restrict__ bhhf,
    const float* __restrict__ Wb, const float* __restrict__ bihb, const float* __restrict__ bhhb,
    float* __restrict__ xh)
{
    const int lane = threadIdx.x & 63;
    const int wv = __builtin_amdgcn_readfirstlane(threadIdx.x >> 6);
    const int blk = blockIdx.x;          // 0..4095
    const int b = blk >> 5;
    const int t = ((blk & 31) << 6) + lane;

    float xr[II];
    {
        const float4* xp = (const float4*)(x + ((size_t)b * TT + t) * II);
        #pragma unroll
        for (int k4 = 0; k4 < II / 4; ++k4) {
            float4 v = xp[k4];
            xr[4*k4+0] = v.x; xr[4*k4+1] = v.y; xr[4*k4+2] = v.z; xr[4*k4+3] = v.w;
        }
    }
    float* outF = xh + (size_t)b * HH * TT + t;
    float* outB = xh + (size_t)(BB + b) * HH * TT + t;
    #pragma unroll 4
    for (int ii = 0; ii < 16; ++ii) {
        const int i = wv * 16 + ii;                    // wave-uniform -> scalar W loads
        const float* wfr = Wf + i * II;
        const float* wbr = Wb + i * II;
        float af0 = bihf[i] + bhhf[i], af1 = 0.f;
        float ab0 = bihb[i] + bhhb[i], ab1 = 0.f;
        #pragma unroll
        for (int k = 0; k < II; k += 2) {
            af0 = fmaf(wfr[k],   xr[k],   af0);
            af1 = fmaf(wfr[k+1], xr[k+1], af1);
            ab0 = fmaf(wbr[k],   xr[k],   ab0);
            ab1 = fmaf(wbr[k+1], xr[k+1], ab1);
        }
        outF[(size_t)i * TT] = af0 + af1;   // coalesced 256B store
        outB[(size_t)i * TT] = ab0 + ab1;
    }
}

// ---------------- general-W fallback (serial chain), R2-proven ----------------
#define RNN_STEP(XOV, HQ, CURBUF, NXTBUF) {                                   \
    float a0 = (XOV), a1 = 0.f, a2 = 0.f, a3 = 0.f;                           \
    const float* hs = hsh[CURBUF];                                            \
    _Pragma("unroll")                                                         \
    for (int j4 = 0; j4 < HH / 4; ++j4) {                                     \
        float4 h4 = *(const float4*)(hs + 4 * j4);  /* ds_read_b128 bcast */  \
        a0 = fmaf(w[4*j4+0], h4.x, a0);                                       \
        a1 = fmaf(w[4*j4+1], h4.y, a1);                                       \
        a2 = fmaf(w[4*j4+2], h4.z, a2);                                       \
        a3 = fmaf(w[4*j4+3], h4.w, a3);                                       \
    }                                                                         \
    HQ = fmaxf((a0 + a1) + (a2 + a3), 0.0f);                                  \
    hsh[NXTBUF][lane] = HQ;                                                   \
}

template<int DIR>
__device__ __noinline__ void rnn_serial(const float* __restrict__ W,
                                        float* __restrict__ xh,
                                        int b, int lane)
{
    float w[HH];
    {
        const float4* wp = (const float4*)(W + lane * HH);
        #pragma unroll
        for (int j4 = 0; j4 < HH / 4; ++j4) {
            float4 v = wp[j4];
            w[4*j4+0] = v.x; w[4*j4+1] = v.y; w[4*j4+2] = v.z; w[4*j4+3] = v.w;
        }
    }
    float* base = xh + ((size_t)(DIR * BB + b) * HH + lane) * TT;

    __shared__ __align__(16) float hsh[2][HH];
    hsh[0][lane] = 0.0f;
    __syncthreads();

    constexpr int STEP = DIR ? -4 : 4;
    int gbase = DIR ? (TT - 4) : 0;
    float4 xq = *(const float4*)(base + gbase);

    for (int g = 0; g < TT / 4; ++g) {
        const int gnext = (g + 1 < TT / 4) ? (gbase + STEP) : gbase;
        const float4 xn = *(const float4*)(base + gnext);

        float hq0, hq1, hq2, hq3;
        if (DIR == 0) {
            RNN_STEP(xq.x, hq0, 0, 1)
            RNN_STEP(xq.y, hq1, 1, 0)
            RNN_STEP(xq.z, hq2, 0, 1)
            RNN_STEP(xq.w, hq3, 1, 0)
        } else {
            RNN_STEP(xq.w, hq0, 0, 1)
            RNN_STEP(xq.z, hq1, 1, 0)
            RNN_STEP(xq.y, hq2, 0, 1)
            RNN_STEP(xq.x, hq3, 1, 0)
        }

        float4 st;
        if (DIR == 0) { st.x = hq0; st.y = hq1; st.z = hq2; st.w = hq3; }
        else          { st.x = hq3; st.y = hq2; st.z = hq1; st.w = hq0; }
        *(float4*)(base + gbase) = st;

        gbase = gnext;
        xq = xn;
    }
}

// ---------------- rnn: identity fast-path (parallel scan) + fallback ----------
__global__ __launch_bounds__(64) void rnn_kernel(
    const float* __restrict__ Whf, const float* __restrict__ Whb,
    float* __restrict__ xh)
{
    const int lane = threadIdx.x;
    const int row  = blockIdx.x;         // 0..16383
    const int dir  = row >> 13;
    const int rid  = row & 8191;
    const int b    = rid >> 6;
    const int hrow = rid & 63;
    const float* W = dir ? Whb : Whf;

    bool ok = true;
    {
        const float4* wp = (const float4*)(W + lane * HH);
        #pragma unroll
        for (int j4 = 0; j4 < HH / 4; ++j4) {
            float4 v = wp[j4];
            ok &= (v.x == ((4*j4+0 == lane) ? 1.0f : 0.0f));
            ok &= (v.y == ((4*j4+1 == lane) ? 1.0f : 0.0f));
            ok &= (v.z == ((4*j4+2 == lane) ? 1.0f : 0.0f));
            ok &= (v.w == ((4*j4+3 == lane) ? 1.0f : 0.0f));
        }
    }
    const bool isI = (__ballot(ok) == ~0ull);

    if (!isI) {
        if (hrow != 0) return;
        if (dir == 0) rnn_serial<0>(Whf, xh, b, lane);
        else          rnn_serial<1>(Whb, xh, b, lane);
        return;
    }

    float* base = xh + ((size_t)(dir * BB + b) * HH + hrow) * TT;

    float a[32];
    if (dir == 0) {
        const float4* xp = (const float4*)(base + lane * 32);
        #pragma unroll
        for (int q = 0; q < 8; ++q) {
            float4 v = xp[q];
            a[4*q+0] = v.x; a[4*q+1] = v.y; a[4*q+2] = v.z; a[4*q+3] = v.w;
        }
    } else {
        const float4* xp = (const float4*)(base + (TT - 32 - lane * 32));
        #pragma unroll
        for (int q = 0; q < 8; ++q) {
            float4 v = xp[q];
            a[31-4*q] = v.x; a[30-4*q] = v.y; a[29-4*q] = v.z; a[28-4*q] = v.w;
        }
    }

    float A = 0.0f, Bv = -__builtin_inff();
    #pragma unroll
    for (int j = 0; j < 32; ++j) {
        A  = A + a[j];
        Bv = fmaxf(Bv + a[j], 0.0f);
    }

    #pragma unroll
    for (int off = 1; off < 64; off <<= 1) {
        float Au = __shfl_up(A,  (unsigned)off);
        float Bu = __shfl_up(Bv, (unsigned)off);
        if (lane >= off) {
            Bv = fmaxf(Bu + A, Bv);
            A  = Au + A;
        }
    }

    float Ae = __shfl_up(A, 1u);
    float Be = __shfl_up(Bv, 1u);
    float h = (lane == 0) ? 0.0f : fmaxf(Ae, Be);

    #pragma unroll
    for (int j = 0; j < 32; ++j) {
        h = fmaxf(h + a[j], 0.0f);
        a[j] = h;
    }

    if (dir == 0) {
        float4* op = (float4*)(base + lane * 32);
        #pragma unroll
        for (int q = 0; q < 8; ++q) {
            float4 st; st.x = a[4*q+0]; st.y = a[4*q+1]; st.z = a[4*q+2]; st.w = a[4*q+3];
            op[q] = st;
        }
    } else {
        float4* op = (float4*)(base + (TT - 32 - lane * 32));
        #pragma unroll
        for (int q = 0; q < 8; ++q) {
            float4 st; st.x = a[31-4*q]; st.y = a[30-4*q]; st.z = a[29-4*q]; st.w = a[28-4*q];
            op[q] = st;
        }
    }
}

// ---------------- mlp: h in LDS, k split across waves, named accs ------------
// R5-R7 post-mortem chain: the RA refuses to keep >~50 load results live
// across a loop (VGPR counts 84/84/48; loads re-sunk every time). So stop
// fighting it: h lives in LDS (remat impossible). Block = 64 t (lane=t),
// 32 KB LDS tile hsh[j][t]. Wave w owns k-rows [32w,32w+32) end-to-end:
// 2 sub-tiles x 16 NAMED accumulators, full j-sum -> leaky -> w1-fma.
// Per j: 1 ds_read_b32 feeds 16 FMAs; w0 rows wave-uniform -> s_loads.
// Final: 4-way oa reduce via LDS (preserves k order w0->w3).
#define REP16(M) M(0) M(1) M(2) M(3) M(4) M(5) M(6) M(7) \
                 M(8) M(9) M(10) M(11) M(12) M(13) M(14) M(15)

__global__ __launch_bounds__(256, 4) void mlp_kernel(
    const float* __restrict__ xh,
    const float* __restrict__ w0, const float* __restrict__ b0,
    const float* __restrict__ w1, const float* __restrict__ b1,
    float* __restrict__ out)
{
    const int tid  = threadIdx.x;
    const int lane = tid & 63;
    const int wid  = __builtin_amdgcn_readfirstlane(tid >> 6); // 0..3
    const int tile = blockIdx.x;          // 0..4095
    const int b    = tile >> 5;
    const int t0   = (tile & 31) << 6;

    __shared__ float hsh[2 * HH][64];     // [j][t] — b32 reads are 2-way (free)
    __shared__ float red[4][64];

    // cooperative load: 8192 floats; per wave j is uniform, t coalesced 256B
    {
        const float* pf = xh + (size_t)b * HH * TT + t0;
        const float* pb = xh + (size_t)(BB + b) * HH * TT + t0;
        #pragma unroll
        for (int it = 0; it < 32; ++it) {
            const int idx = it * 256 + tid;
            const int j = idx >> 6, tt = idx & 63;
            hsh[j][tt] = (j < HH) ? pf[(size_t)j * TT + tt]
                                  : pb[(size_t)(j - HH) * TT + tt];
        }
    }
    __syncthreads();

    float oa = 0.0f;

    #pragma unroll 1
    for (int s = 0; s < 2; ++s) {
        const int kbase = wid * 32 + s * 16;
        const float* wk = w0 + kbase * 128;    // wave-uniform -> s_loads

        #define DC(i) float c##i = b0[kbase + i];
        REP16(DC)
        #undef DC

        #pragma unroll 4
        for (int jg = 0; jg < 32; ++jg) {
            const float hA = hsh[4*jg+0][lane];
            const float hB = hsh[4*jg+1][lane];
            const float hC = hsh[4*jg+2][lane];
            const float hD = hsh[4*jg+3][lane];
            #define WF(i) { float4 wq = *(const float4*)(wk + 4*jg + (i)*128); \
                            c##i = fmaf(wq.x, hA, c##i);                       \
                            c##i = fmaf(wq.y, hB, c##i);                       \
                            c##i = fmaf(wq.z, hC, c##i);                       \
                            c##i = fmaf(wq.w, hD, c##i); }
            REP16(WF)
            #undef WF
        }

        #define EP(i) { float v = fmaxf(c##i, 0.01f * c##i); \
                        oa = fmaf(v, w1[kbase + i], oa); }
        REP16(EP)
        #undef EP
    }

    red[wid][lane] = oa;
    __syncthreads();
    if (wid == 0) {
        float r = ((red[0][lane] + red[1][lane]) + red[2][lane]) + red[3][lane];
        out[(size_t)b * TT + t0 + lane] = r + b1[0];
    }
}

extern "C" void kernel_launch(void* const* d_in, const int* in_sizes, int n_in,
                              void* d_out, int out_size, void* d_ws, size_t ws_size,
                              hipStream_t stream) {
    (void)in_sizes; (void)n_in; (void)out_size; (void)ws_size;
    const float* x    = (const float*)d_in[0];
    const float* Wihf = (const float*)d_in[1];
    const float* Whhf = (const float*)d_in[2];
    const float* bihf = (const float*)d_in[3];
    const float* bhhf = (const float*)d_in[4];
    const float* Wihb = (const float*)d_in[5];
    const float* Whhb = (const float*)d_in[6];
    const float* bihb = (const float*)d_in[7];
    const float* bhhb = (const float*)d_in[8];
    const float* ff0w = (const float*)d_in[9];
    const float* ff0b = (const float*)d_in[10];
    const float* ff1w = (const float*)d_in[11];
    const float* ff1b = (const float*)d_in[12];
    float* xh = (float*)d_ws;

    proj_kernel<<<dim3(BB * (TT / 64)), dim3(256), 0, stream>>>(
        x, Wihf, bihf, bhhf, Wihb, bihb, bhhb, xh);
    rnn_kernel<<<dim3(2 * BB * HH), dim3(64), 0, stream>>>(Whhf, Whhb, xh);
    mlp_kernel<<<dim3(BB * (TT / 64)), dim3(256), 0, stream>>>(
        xh, ff0w, ff0b, ff1w, ff1b, (float*)d_out);
}

// Round 9
// 518.362 us; speedup vs baseline: 1.1754x; 1.1754x over previous
//
#include <hip/hip_runtime.h>

#define BB 128
#define TT 2048
#define II 32
#define HH 64

// ws layout: float xh[2][BB][HH][TT]   (xw written by proj, overwritten in-place by h in rnn)
// total = 2*128*64*2048*4 = 128 MiB

__global__ __launch_bounds__(256) void proj_kernel(
    const float* __restrict__ x,
    const float* __restrict__ Wf, const float* __restrict__ bihf, const float* __restrict__ bhhf,
    const float* __restrict__ Wb, const float* __restrict__ bihb, const float* __restrict__ bhhb,
    float* __restrict__ xh)
{
    const int lane = threadIdx.x & 63;
    const int wv = __builtin_amdgcn_readfirstlane(threadIdx.x >> 6);
    const int blk = blockIdx.x;          // 0..4095
    const int b = blk >> 5;
    const int t = ((blk & 31) << 6) + lane;

    float xr[II];
    {
        const float4* xp = (const float4*)(x + ((size_t)b * TT + t) * II);
        #pragma unroll
        for (int k4 = 0; k4 < II / 4; ++k4) {
            float4 v = xp[k4];
            xr[4*k4+0] = v.x; xr[4*k4+1] = v.y; xr[4*k4+2] = v.z; xr[4*k4+3] = v.w;
        }
    }
    float* outF = xh + (size_t)b * HH * TT + t;
    float* outB = xh + (size_t)(BB + b) * HH * TT + t;
    #pragma unroll 4
    for (int ii = 0; ii < 16; ++ii) {
        const int i = wv * 16 + ii;                    // wave-uniform -> scalar W loads
        const float* wfr = Wf + i * II;
        const float* wbr = Wb + i * II;
        float af0 = bihf[i] + bhhf[i], af1 = 0.f;
        float ab0 = bihb[i] + bhhb[i], ab1 = 0.f;
        #pragma unroll
        for (int k = 0; k < II; k += 2) {
            af0 = fmaf(wfr[k],   xr[k],   af0);
            af1 = fmaf(wfr[k+1], xr[k+1], af1);
            ab0 = fmaf(wbr[k],   xr[k],   ab0);
            ab1 = fmaf(wbr[k+1], xr[k+1], ab1);
        }
        outF[(size_t)i * TT] = af0 + af1;   // coalesced 256B store
        outB[(size_t)i * TT] = ab0 + ab1;
    }
}

// ---------------- general-W fallback (serial chain), R2-proven ----------------
#define RNN_STEP(XOV, HQ, CURBUF, NXTBUF) {                                   \
    float a0 = (XOV), a1 = 0.f, a2 = 0.f, a3 = 0.f;                           \
    const float* hs = hsh[CURBUF];                                            \
    _Pragma("unroll")                                                         \
    for (int j4 = 0; j4 < HH / 4; ++j4) {                                     \
        float4 h4 = *(const float4*)(hs + 4 * j4);  /* ds_read_b128 bcast */  \
        a0 = fmaf(w[4*j4+0], h4.x, a0);                                       \
        a1 = fmaf(w[4*j4+1], h4.y, a1);                                       \
        a2 = fmaf(w[4*j4+2], h4.z, a2);                                       \
        a3 = fmaf(w[4*j4+3], h4.w, a3);                                       \
    }                                                                         \
    HQ = fmaxf((a0 + a1) + (a2 + a3), 0.0f);                                  \
    hsh[NXTBUF][lane] = HQ;                                                   \
}

template<int DIR>
__device__ __noinline__ void rnn_serial(const float* __restrict__ W,
                                        float* __restrict__ xh,
                                        int b, int lane)
{
    float w[HH];
    {
        const float4* wp = (const float4*)(W + lane * HH);
        #pragma unroll
        for (int j4 = 0; j4 < HH / 4; ++j4) {
            float4 v = wp[j4];
            w[4*j4+0] = v.x; w[4*j4+1] = v.y; w[4*j4+2] = v.z; w[4*j4+3] = v.w;
        }
    }
    float* base = xh + ((size_t)(DIR * BB + b) * HH + lane) * TT;

    __shared__ __align__(16) float hsh[2][HH];
    hsh[0][lane] = 0.0f;
    __syncthreads();

    constexpr int STEP = DIR ? -4 : 4;
    int gbase = DIR ? (TT - 4) : 0;
    float4 xq = *(const float4*)(base + gbase);

    for (int g = 0; g < TT / 4; ++g) {
        const int gnext = (g + 1 < TT / 4) ? (gbase + STEP) : gbase;
        const float4 xn = *(const float4*)(base + gnext);

        float hq0, hq1, hq2, hq3;
        if (DIR == 0) {
            RNN_STEP(xq.x, hq0, 0, 1)
            RNN_STEP(xq.y, hq1, 1, 0)
            RNN_STEP(xq.z, hq2, 0, 1)
            RNN_STEP(xq.w, hq3, 1, 0)
        } else {
            RNN_STEP(xq.w, hq0, 0, 1)
            RNN_STEP(xq.z, hq1, 1, 0)
            RNN_STEP(xq.y, hq2, 0, 1)
            RNN_STEP(xq.x, hq3, 1, 0)
        }

        float4 st;
        if (DIR == 0) { st.x = hq0; st.y = hq1; st.z = hq2; st.w = hq3; }
        else          { st.x = hq3; st.y = hq2; st.z = hq1; st.w = hq0; }
        *(float4*)(base + gbase) = st;

        gbase = gnext;
        xq = xn;
    }
}

// ---------------- rnn: identity fast-path (parallel scan) + fallback ----------
__global__ __launch_bounds__(64) void rnn_kernel(
    const float* __restrict__ Whf, const float* __restrict__ Whb,
    float* __restrict__ xh)
{
    const int lane = threadIdx.x;
    const int row  = blockIdx.x;         // 0..16383
    const int dir  = row >> 13;
    const int rid  = row & 8191;
    const int b    = rid >> 6;
    const int hrow = rid & 63;
    const float* W = dir ? Whb : Whf;

    bool ok = true;
    {
        const float4* wp = (const float4*)(W + lane * HH);
        #pragma unroll
        for (int j4 = 0; j4 < HH / 4; ++j4) {
            float4 v = wp[j4];
            ok &= (v.x == ((4*j4+0 == lane) ? 1.0f : 0.0f));
            ok &= (v.y == ((4*j4+1 == lane) ? 1.0f : 0.0f));
            ok &= (v.z == ((4*j4+2 == lane) ? 1.0f : 0.0f));
            ok &= (v.w == ((4*j4+3 == lane) ? 1.0f : 0.0f));
        }
    }
    const bool isI = (__ballot(ok) == ~0ull);

    if (!isI) {
        if (hrow != 0) return;
        if (dir == 0) rnn_serial<0>(Whf, xh, b, lane);
        else          rnn_serial<1>(Whb, xh, b, lane);
        return;
    }

    float* base = xh + ((size_t)(dir * BB + b) * HH + hrow) * TT;

    float a[32];
    if (dir == 0) {
        const float4* xp = (const float4*)(base + lane * 32);
        #pragma unroll
        for (int q = 0; q < 8; ++q) {
            float4 v = xp[q];
            a[4*q+0] = v.x; a[4*q+1] = v.y; a[4*q+2] = v.z; a[4*q+3] = v.w;
        }
    } else {
        const float4* xp = (const float4*)(base + (TT - 32 - lane * 32));
        #pragma unroll
        for (int q = 0; q < 8; ++q) {
            float4 v = xp[q];
            a[31-4*q] = v.x; a[30-4*q] = v.y; a[29-4*q] = v.z; a[28-4*q] = v.w;
        }
    }

    float A = 0.0f, Bv = -__builtin_inff();
    #pragma unroll
    for (int j = 0; j < 32; ++j) {
        A  = A + a[j];
        Bv = fmaxf(Bv + a[j], 0.0f);
    }

    #pragma unroll
    for (int off = 1; off < 64; off <<= 1) {
        float Au = __shfl_up(A,  (unsigned)off);
        float Bu = __shfl_up(Bv, (unsigned)off);
        if (lane >= off) {
            Bv = fmaxf(Bu + A, Bv);
            A  = Au + A;
        }
    }

    float Ae = __shfl_up(A, 1u);
    float Be = __shfl_up(Bv, 1u);
    float h = (lane == 0) ? 0.0f : fmaxf(Ae, Be);

    #pragma unroll
    for (int j = 0; j < 32; ++j) {
        h = fmaxf(h + a[j], 0.0f);
        a[j] = h;
    }

    if (dir == 0) {
        float4* op = (float4*)(base + lane * 32);
        #pragma unroll
        for (int q = 0; q < 8; ++q) {
            float4 st; st.x = a[4*q+0]; st.y = a[4*q+1]; st.z = a[4*q+2]; st.w = a[4*q+3];
            op[q] = st;
        }
    } else {
        float4* op = (float4*)(base + (TT - 32 - lane * 32));
        #pragma unroll
        for (int q = 0; q < 8; ++q) {
            float4 st; st.x = a[31-4*q]; st.y = a[30-4*q]; st.z = a[29-4*q]; st.w = a[28-4*q];
            op[q] = st;
        }
    }
}

// ---------------- mlp: 64 NAMED ACCUMULATORS, 2 k-passes ---------------------
// Evidence from R3-R8: the RA sinks LOAD results (h) it won't hold live, but
// it CANNOT sink accumulators (loop-carried). So invert: pressure goes into
// 64 named accs (k-half per pass); h is transient (4 scalars per j-group,
// each reused by 64 FMAs); w0 stays wave-uniform s_loads in 4 sequential
// banks of 16 float4 (64 SGPRs in flight — R5-proven; R8's 256 overflowed
// the 112-SGPR file and fell off the scalar path). Pass 2 re-reads xh from
// L3 (128 MiB < 256 MiB). Epilogue ascending k => summation identical to R5.
#define REP16_2(M, X) M(0,X) M(1,X) M(2,X) M(3,X) M(4,X) M(5,X) M(6,X) M(7,X) \
                      M(8,X) M(9,X) M(10,X) M(11,X) M(12,X) M(13,X) M(14,X) M(15,X)

#define WFA(i, OFF) { float4 wq = *(const float4*)(wkA + (OFF) + (i)*128); \
    cA##i = fmaf(wq.x, hA, cA##i); cA##i = fmaf(wq.y, hB, cA##i);          \
    cA##i = fmaf(wq.z, hC, cA##i); cA##i = fmaf(wq.w, hD, cA##i); }
#define WFB(i, OFF) { float4 wq = *(const float4*)(wkB + (OFF) + (i)*128); \
    cB##i = fmaf(wq.x, hA, cB##i); cB##i = fmaf(wq.y, hB, cB##i);          \
    cB##i = fmaf(wq.z, hC, cB##i); cB##i = fmaf(wq.w, hD, cB##i); }
#define WFC(i, OFF) { float4 wq = *(const float4*)(wkC + (OFF) + (i)*128); \
    cC##i = fmaf(wq.x, hA, cC##i); cC##i = fmaf(wq.y, hB, cC##i);          \
    cC##i = fmaf(wq.z, hC, cC##i); cC##i = fmaf(wq.w, hD, cC##i); }
#define WFD(i, OFF) { float4 wq = *(const float4*)(wkD + (OFF) + (i)*128); \
    cD##i = fmaf(wq.x, hA, cD##i); cD##i = fmaf(wq.y, hB, cD##i);          \
    cD##i = fmaf(wq.z, hC, cD##i); cD##i = fmaf(wq.w, hD, cD##i); }

__global__ __launch_bounds__(256, 2) void mlp_kernel(
    const float* __restrict__ xh,
    const float* __restrict__ w0, const float* __restrict__ b0,
    const float* __restrict__ w1, const float* __restrict__ b1,
    float* __restrict__ out)
{
    const int lane = threadIdx.x & 63;
    const int tile = __builtin_amdgcn_readfirstlane(blockIdx.x * 4 + (threadIdx.x >> 6));
    const int b = tile >> 5;
    const int t = ((tile & 31) << 6) + lane;

    const float* pf = xh + (size_t)b * HH * TT + t;        // forward h, stride TT per j
    const float* pb = xh + (size_t)(BB + b) * HH * TT + t; // backward h

    float oa = 0.0f;

    #pragma unroll 1
    for (int half = 0; half < 2; ++half) {
        const int kb = half * 64;
        const float* wkA = w0 + (size_t)(kb +  0) * 128;   // wave-uniform bases
        const float* wkB = w0 + (size_t)(kb + 16) * 128;
        const float* wkC = w0 + (size_t)(kb + 32) * 128;
        const float* wkD = w0 + (size_t)(kb + 48) * 128;

        #define DCA(i, X) float cA##i = b0[kb + i];
        #define DCB(i, X) float cB##i = b0[kb + 16 + i];
        #define DCC(i, X) float cC##i = b0[kb + 32 + i];
        #define DCD(i, X) float cD##i = b0[kb + 48 + i];
        REP16_2(DCA, 0) REP16_2(DCB, 0) REP16_2(DCC, 0) REP16_2(DCD, 0)
        #undef DCA
        #undef DCB
        #undef DCC
        #undef DCD

        // forward half of j: 0..63
        #pragma unroll 1
        for (int jg = 0; jg < 16; ++jg) {
            const float hA = pf[(size_t)(4*jg+0) * TT];
            const float hB = pf[(size_t)(4*jg+1) * TT];
            const float hC = pf[(size_t)(4*jg+2) * TT];
            const float hD = pf[(size_t)(4*jg+3) * TT];
            const int off = 4 * jg;
            REP16_2(WFA, off) REP16_2(WFB, off) REP16_2(WFC, off) REP16_2(WFD, off)
        }
        // backward half of j: 64..127
        #pragma unroll 1
        for (int jg = 0; jg < 16; ++jg) {
            const float hA = pb[(size_t)(4*jg+0) * TT];
            const float hB = pb[(size_t)(4*jg+1) * TT];
            const float hC = pb[(size_t)(4*jg+2) * TT];
            const float hD = pb[(size_t)(4*jg+3) * TT];
            const int off = 64 + 4 * jg;
            REP16_2(WFA, off) REP16_2(WFB, off) REP16_2(WFC, off) REP16_2(WFD, off)
        }

        // leaky_relu + second layer, ascending k (same order as R5)
        #define EPA(i, X) { float v = fmaxf(cA##i, 0.01f * cA##i); oa = fmaf(v, w1[kb + i],      oa); }
        #define EPB(i, X) { float v = fmaxf(cB##i, 0.01f * cB##i); oa = fmaf(v, w1[kb + 16 + i], oa); }
        #define EPC(i, X) { float v = fmaxf(cC##i, 0.01f * cC##i); oa = fmaf(v, w1[kb + 32 + i], oa); }
        #define EPD(i, X) { float v = fmaxf(cD##i, 0.01f * cD##i); oa = fmaf(v, w1[kb + 48 + i], oa); }
        REP16_2(EPA, 0) REP16_2(EPB, 0) REP16_2(EPC, 0) REP16_2(EPD, 0)
        #undef EPA
        #undef EPB
        #undef EPC
        #undef EPD
    }

    out[(size_t)b * TT + t] = oa + b1[0];
}

extern "C" void kernel_launch(void* const* d_in, const int* in_sizes, int n_in,
                              void* d_out, int out_size, void* d_ws, size_t ws_size,
                              hipStream_t stream) {
    (void)in_sizes; (void)n_in; (void)out_size; (void)ws_size;
    const float* x    = (const float*)d_in[0];
    const float* Wihf = (const float*)d_in[1];
    const float* Whhf = (const float*)d_in[2];
    const float* bihf = (const float*)d_in[3];
    const float* bhhf = (const float*)d_in[4];
    const float* Wihb = (const float*)d_in[5];
    const float* Whhb = (const float*)d_in[6];
    const float* bihb = (const float*)d_in[7];
    const float* bhhb = (const float*)d_in[8];
    const float* ff0w = (const float*)d_in[9];
    const float* ff0b = (const float*)d_in[10];
    const float* ff1w = (const float*)d_in[11];
    const float* ff1b = (const float*)d_in[12];
    float* xh = (float*)d_ws;

    proj_kernel<<<dim3(BB * (TT / 64)), dim3(256), 0, stream>>>(
        x, Wihf, bihf, bhhf, Wihb, bihb, bhhb, xh);
    rnn_kernel<<<dim3(2 * BB * HH), dim3(64), 0, stream>>>(Whhf, Whhb, xh);
    mlp_kernel<<<dim3(BB * (TT / 64) / 4), dim3(256), 0, stream>>>(
        xh, ff0w, ff0b, ff1w, ff1b, (float*)d_out);
}

// Round 10
// 368.450 us; speedup vs baseline: 1.6537x; 1.4069x over previous
//
#include <hip/hip_runtime.h>

#define BB 128
#define TT 2048
#define II 32
#define HH 64

// ws layout: float xh[2][BB][HH][TT]   (xw written by proj, overwritten in-place by h in rnn)
// total = 2*128*64*2048*4 = 128 MiB

__global__ __launch_bounds__(256) void proj_kernel(
    const float* __restrict__ x,
    const float* __restrict__ Wf, const float* __restrict__ bihf, const float* __restrict__ bhhf,
    const float* __restrict__ Wb, const float* __restrict__ bihb, const float* __restrict__ bhhb,
    float* __restrict__ xh)
{
    const int lane = threadIdx.x & 63;
    const int wv = __builtin_amdgcn_readfirstlane(threadIdx.x >> 6);
    const int blk = blockIdx.x;          // 0..4095
    const int b = blk >> 5;
    const int t = ((blk & 31) << 6) + lane;

    float xr[II];
    {
        const float4* xp = (const float4*)(x + ((size_t)b * TT + t) * II);
        #pragma unroll
        for (int k4 = 0; k4 < II / 4; ++k4) {
            float4 v = xp[k4];
            xr[4*k4+0] = v.x; xr[4*k4+1] = v.y; xr[4*k4+2] = v.z; xr[4*k4+3] = v.w;
        }
    }
    float* outF = xh + (size_t)b * HH * TT + t;
    float* outB = xh + (size_t)(BB + b) * HH * TT + t;
    #pragma unroll 4
    for (int ii = 0; ii < 16; ++ii) {
        const int i = wv * 16 + ii;                    // wave-uniform -> scalar W loads
        const float* wfr = Wf + i * II;
        const float* wbr = Wb + i * II;
        float af0 = bihf[i] + bhhf[i], af1 = 0.f;
        float ab0 = bihb[i] + bhhb[i], ab1 = 0.f;
        #pragma unroll
        for (int k = 0; k < II; k += 2) {
            af0 = fmaf(wfr[k],   xr[k],   af0);
            af1 = fmaf(wfr[k+1], xr[k+1], af1);
            ab0 = fmaf(wbr[k],   xr[k],   ab0);
            ab1 = fmaf(wbr[k+1], xr[k+1], ab1);
        }
        outF[(size_t)i * TT] = af0 + af1;   // coalesced 256B store
        outB[(size_t)i * TT] = ab0 + ab1;
    }
}

// ---------------- general-W fallback (serial chain), R2-proven ----------------
#define RNN_STEP(XOV, HQ, CURBUF, NXTBUF) {                                   \
    float a0 = (XOV), a1 = 0.f, a2 = 0.f, a3 = 0.f;                           \
    const float* hs = hsh[CURBUF];                                            \
    _Pragma("unroll")                                                         \
    for (int j4 = 0; j4 < HH / 4; ++j4) {                                     \
        float4 h4 = *(const float4*)(hs + 4 * j4);  /* ds_read_b128 bcast */  \
        a0 = fmaf(w[4*j4+0], h4.x, a0);                                       \
        a1 = fmaf(w[4*j4+1], h4.y, a1);                                       \
        a2 = fmaf(w[4*j4+2], h4.z, a2);                                       \
        a3 = fmaf(w[4*j4+3], h4.w, a3);                                       \
    }                                                                         \
    HQ = fmaxf((a0 + a1) + (a2 + a3), 0.0f);                                  \
    hsh[NXTBUF][lane] = HQ;                                                   \
}

template<int DIR>
__device__ __noinline__ void rnn_serial(const float* __restrict__ W,
                                        float* __restrict__ xh,
                                        int b, int lane)
{
    float w[HH];
    {
        const float4* wp = (const float4*)(W + lane * HH);
        #pragma unroll
        for (int j4 = 0; j4 < HH / 4; ++j4) {
            float4 v = wp[j4];
            w[4*j4+0] = v.x; w[4*j4+1] = v.y; w[4*j4+2] = v.z; w[4*j4+3] = v.w;
        }
    }
    float* base = xh + ((size_t)(DIR * BB + b) * HH + lane) * TT;

    __shared__ __align__(16) float hsh[2][HH];
    hsh[0][lane] = 0.0f;
    __syncthreads();

    constexpr int STEP = DIR ? -4 : 4;
    int gbase = DIR ? (TT - 4) : 0;
    float4 xq = *(const float4*)(base + gbase);

    for (int g = 0; g < TT / 4; ++g) {
        const int gnext = (g + 1 < TT / 4) ? (gbase + STEP) : gbase;
        const float4 xn = *(const float4*)(base + gnext);

        float hq0, hq1, hq2, hq3;
        if (DIR == 0) {
            RNN_STEP(xq.x, hq0, 0, 1)
            RNN_STEP(xq.y, hq1, 1, 0)
            RNN_STEP(xq.z, hq2, 0, 1)
            RNN_STEP(xq.w, hq3, 1, 0)
        } else {
            RNN_STEP(xq.w, hq0, 0, 1)
            RNN_STEP(xq.z, hq1, 1, 0)
            RNN_STEP(xq.y, hq2, 0, 1)
            RNN_STEP(xq.x, hq3, 1, 0)
        }

        float4 st;
        if (DIR == 0) { st.x = hq0; st.y = hq1; st.z = hq2; st.w = hq3; }
        else          { st.x = hq3; st.y = hq2; st.z = hq1; st.w = hq0; }
        *(float4*)(base + gbase) = st;

        gbase = gnext;
        xq = xn;
    }
}

// ---------------- rnn: identity fast-path (parallel scan) + fallback ----------
__global__ __launch_bounds__(64) void rnn_kernel(
    const float* __restrict__ Whf, const float* __restrict__ Whb,
    float* __restrict__ xh)
{
    const int lane = threadIdx.x;
    const int row  = blockIdx.x;         // 0..16383
    const int dir  = row >> 13;
    const int rid  = row & 8191;
    const int b    = rid >> 6;
    const int hrow = rid & 63;
    const float* W = dir ? Whb : Whf;

    bool ok = true;
    {
        const float4* wp = (const float4*)(W + lane * HH);
        #pragma unroll
        for (int j4 = 0; j4 < HH / 4; ++j4) {
            float4 v = wp[j4];
            ok &= (v.x == ((4*j4+0 == lane) ? 1.0f : 0.0f));
            ok &= (v.y == ((4*j4+1 == lane) ? 1.0f : 0.0f));
            ok &= (v.z == ((4*j4+2 == lane) ? 1.0f : 0.0f));
            ok &= (v.w == ((4*j4+3 == lane) ? 1.0f : 0.0f));
        }
    }
    const bool isI = (__ballot(ok) == ~0ull);

    if (!isI) {
        if (hrow != 0) return;
        if (dir == 0) rnn_serial<0>(Whf, xh, b, lane);
        else          rnn_serial<1>(Whb, xh, b, lane);
        return;
    }

    float* base = xh + ((size_t)(dir * BB + b) * HH + hrow) * TT;

    float a[32];
    if (dir == 0) {
        const float4* xp = (const float4*)(base + lane * 32);
        #pragma unroll
        for (int q = 0; q < 8; ++q) {
            float4 v = xp[q];
            a[4*q+0] = v.x; a[4*q+1] = v.y; a[4*q+2] = v.z; a[4*q+3] = v.w;
        }
    } else {
        const float4* xp = (const float4*)(base + (TT - 32 - lane * 32));
        #pragma unroll
        for (int q = 0; q < 8; ++q) {
            float4 v = xp[q];
            a[31-4*q] = v.x; a[30-4*q] = v.y; a[29-4*q] = v.z; a[28-4*q] = v.w;
        }
    }

    float A = 0.0f, Bv = -__builtin_inff();
    #pragma unroll
    for (int j = 0; j < 32; ++j) {
        A  = A + a[j];
        Bv = fmaxf(Bv + a[j], 0.0f);
    }

    #pragma unroll
    for (int off = 1; off < 64; off <<= 1) {
        float Au = __shfl_up(A,  (unsigned)off);
        float Bu = __shfl_up(Bv, (unsigned)off);
        if (lane >= off) {
            Bv = fmaxf(Bu + A, Bv);
            A  = Au + A;
        }
    }

    float Ae = __shfl_up(A, 1u);
    float Be = __shfl_up(Bv, 1u);
    float h = (lane == 0) ? 0.0f : fmaxf(Ae, Be);

    #pragma unroll
    for (int j = 0; j < 32; ++j) {
        h = fmaxf(h + a[j], 0.0f);
        a[j] = h;
    }

    if (dir == 0) {
        float4* op = (float4*)(base + lane * 32);
        #pragma unroll
        for (int q = 0; q < 8; ++q) {
            float4 st; st.x = a[4*q+0]; st.y = a[4*q+1]; st.z = a[4*q+2]; st.w = a[4*q+3];
            op[q] = st;
        }
    } else {
        float4* op = (float4*)(base + (TT - 32 - lane * 32));
        #pragma unroll
        for (int q = 0; q < 8; ++q) {
            float4 st; st.x = a[31-4*q]; st.y = a[30-4*q]; st.z = a[29-4*q]; st.w = a[28-4*q];
            op[q] = st;
        }
    }
}

// ---------------- mlp: h in LDS, k split across waves, jg UNROLL 1 -----------
// R8 had the right memory structure (one 66 MB h pass, LDS remat-proof,
// 2-way-free ds_reads) and failed ONLY because `#pragma unroll 4` on the jg
// loop put 64 s_load_dwordx4 (256 SGPRs) in flight -> overflowed the SGPR
// file -> w0 demoted off the scalar path (VALUBusy 85% at 6.6x the FMA
// floor). R5/R7 proved 16 float4 s_loads in flight is safe. This is R8
// with unroll 1 — one 16-s_load bank + 64 FMAs per jg iteration.
#define REP16(M) M(0) M(1) M(2) M(3) M(4) M(5) M(6) M(7) \
                 M(8) M(9) M(10) M(11) M(12) M(13) M(14) M(15)

__global__ __launch_bounds__(256, 4) void mlp_kernel(
    const float* __restrict__ xh,
    const float* __restrict__ w0, const float* __restrict__ b0,
    const float* __restrict__ w1, const float* __restrict__ b1,
    float* __restrict__ out)
{
    const int tid  = threadIdx.x;
    const int lane = tid & 63;
    const int wid  = __builtin_amdgcn_readfirstlane(tid >> 6); // 0..3
    const int tile = blockIdx.x;          // 0..4095
    const int b    = tile >> 5;
    const int t0   = (tile & 31) << 6;

    __shared__ float hsh[2 * HH][64];     // [j][t] — b32 reads are 2-way (free)
    __shared__ float red[4][64];

    // cooperative load: 8192 floats; per wave j is uniform, t coalesced 256B
    {
        const float* pf = xh + (size_t)b * HH * TT + t0;
        const float* pb = xh + (size_t)(BB + b) * HH * TT + t0;
        #pragma unroll
        for (int it = 0; it < 32; ++it) {
            const int idx = it * 256 + tid;
            const int j = idx >> 6, tt = idx & 63;
            hsh[j][tt] = (j < HH) ? pf[(size_t)j * TT + tt]
                                  : pb[(size_t)(j - HH) * TT + tt];
        }
    }
    __syncthreads();

    float oa = 0.0f;

    #pragma unroll 1
    for (int s = 0; s < 2; ++s) {
        const int kbase = wid * 32 + s * 16;
        const float* wk = w0 + (size_t)kbase * 128;    // wave-uniform -> s_loads

        #define DC(i) float c##i = b0[kbase + i];
        REP16(DC)
        #undef DC

        #pragma unroll 1
        for (int jg = 0; jg < 32; ++jg) {
            const float hA = hsh[4*jg+0][lane];
            const float hB = hsh[4*jg+1][lane];
            const float hC = hsh[4*jg+2][lane];
            const float hD = hsh[4*jg+3][lane];
            #define WF(i) { float4 wq = *(const float4*)(wk + 4*jg + (i)*128); \
                            c##i = fmaf(wq.x, hA, c##i);                       \
                            c##i = fmaf(wq.y, hB, c##i);                       \
                            c##i = fmaf(wq.z, hC, c##i);                       \
                            c##i = fmaf(wq.w, hD, c##i); }
            REP16(WF)
            #undef WF
        }

        #define EP(i) { float v = fmaxf(c##i, 0.01f * c##i); \
                        oa = fmaf(v, w1[kbase + i], oa); }
        REP16(EP)
        #undef EP
    }

    red[wid][lane] = oa;
    __syncthreads();
    if (wid == 0) {
        float r = ((red[0][lane] + red[1][lane]) + red[2][lane]) + red[3][lane];
        out[(size_t)b * TT + t0 + lane] = r + b1[0];
    }
}

extern "C" void kernel_launch(void* const* d_in, const int* in_sizes, int n_in,
                              void* d_out, int out_size, void* d_ws, size_t ws_size,
                              hipStream_t stream) {
    (void)in_sizes; (void)n_in; (void)out_size; (void)ws_size;
    const float* x    = (const float*)d_in[0];
    const float* Wihf = (const float*)d_in[1];
    const float* Whhf = (const float*)d_in[2];
    const float* bihf = (const float*)d_in[3];
    const float* bhhf = (const float*)d_in[4];
    const float* Wihb = (const float*)d_in[5];
    const float* Whhb = (const float*)d_in[6];
    const float* bihb = (const float*)d_in[7];
    const float* bhhb = (const float*)d_in[8];
    const float* ff0w = (const float*)d_in[9];
    const float* ff0b = (const float*)d_in[10];
    const float* ff1w = (const float*)d_in[11];
    const float* ff1b = (const float*)d_in[12];
    float* xh = (float*)d_ws;

    proj_kernel<<<dim3(BB * (TT / 64)), dim3(256), 0, stream>>>(
        x, Wihf, bihf, bhhf, Wihb, bihb, bhhb, xh);
    rnn_kernel<<<dim3(2 * BB * HH), dim3(64), 0, stream>>>(Whhf, Whhb, xh);
    mlp_kernel<<<dim3(BB * (TT / 64)), dim3(256), 0, stream>>>(
        xh, ff0w, ff0b, ff1w, ff1b, (float*)d_out);
}

// Round 11
// 329.035 us; speedup vs baseline: 1.8518x; 1.1198x over previous
//
#include <hip/hip_runtime.h>

#define BB 128
#define TT 2048
#define II 32
#define HH 64

// ws layout: float xh[2][BB][HH][TT]   (xw written by proj, overwritten in-place by h in rnn)
// total = 2*128*64*2048*4 = 128 MiB

__global__ __launch_bounds__(256) void proj_kernel(
    const float* __restrict__ x,
    const float* __restrict__ Wf, const float* __restrict__ bihf, const float* __restrict__ bhhf,
    const float* __restrict__ Wb, const float* __restrict__ bihb, const float* __restrict__ bhhb,
    float* __restrict__ xh)
{
    const int lane = threadIdx.x & 63;
    const int wv = __builtin_amdgcn_readfirstlane(threadIdx.x >> 6);
    const int blk = blockIdx.x;          // 0..4095
    const int b = blk >> 5;
    const int t = ((blk & 31) << 6) + lane;

    float xr[II];
    {
        const float4* xp = (const float4*)(x + ((size_t)b * TT + t) * II);
        #pragma unroll
        for (int k4 = 0; k4 < II / 4; ++k4) {
            float4 v = xp[k4];
            xr[4*k4+0] = v.x; xr[4*k4+1] = v.y; xr[4*k4+2] = v.z; xr[4*k4+3] = v.w;
        }
    }
    float* outF = xh + (size_t)b * HH * TT + t;
    float* outB = xh + (size_t)(BB + b) * HH * TT + t;
    #pragma unroll 4
    for (int ii = 0; ii < 16; ++ii) {
        const int i = wv * 16 + ii;                    // wave-uniform -> scalar W loads
        const float* wfr = Wf + i * II;
        const float* wbr = Wb + i * II;
        float af0 = bihf[i] + bhhf[i], af1 = 0.f;
        float ab0 = bihb[i] + bhhb[i], ab1 = 0.f;
        #pragma unroll
        for (int k = 0; k < II; k += 2) {
            af0 = fmaf(wfr[k],   xr[k],   af0);
            af1 = fmaf(wfr[k+1], xr[k+1], af1);
            ab0 = fmaf(wbr[k],   xr[k],   ab0);
            ab1 = fmaf(wbr[k+1], xr[k+1], ab1);
        }
        outF[(size_t)i * TT] = af0 + af1;   // coalesced 256B store
        outB[(size_t)i * TT] = ab0 + ab1;
    }
}

// ---------------- general-W fallback (serial chain), R2-proven ----------------
#define RNN_STEP(XOV, HQ, CURBUF, NXTBUF) {                                   \
    float a0 = (XOV), a1 = 0.f, a2 = 0.f, a3 = 0.f;                           \
    const float* hs = hsh[CURBUF];                                            \
    _Pragma("unroll")                                                         \
    for (int j4 = 0; j4 < HH / 4; ++j4) {                                     \
        float4 h4 = *(const float4*)(hs + 4 * j4);  /* ds_read_b128 bcast */  \
        a0 = fmaf(w[4*j4+0], h4.x, a0);                                       \
        a1 = fmaf(w[4*j4+1], h4.y, a1);                                       \
        a2 = fmaf(w[4*j4+2], h4.z, a2);                                       \
        a3 = fmaf(w[4*j4+3], h4.w, a3);                                       \
    }                                                                         \
    HQ = fmaxf((a0 + a1) + (a2 + a3), 0.0f);                                  \
    hsh[NXTBUF][lane] = HQ;                                                   \
}

template<int DIR>
__device__ __noinline__ void rnn_serial(const float* __restrict__ W,
                                        float* __restrict__ xh,
                                        int b, int lane)
{
    float w[HH];
    {
        const float4* wp = (const float4*)(W + lane * HH);
        #pragma unroll
        for (int j4 = 0; j4 < HH / 4; ++j4) {
            float4 v = wp[j4];
            w[4*j4+0] = v.x; w[4*j4+1] = v.y; w[4*j4+2] = v.z; w[4*j4+3] = v.w;
        }
    }
    float* base = xh + ((size_t)(DIR * BB + b) * HH + lane) * TT;

    __shared__ __align__(16) float hsh[2][HH];
    hsh[0][lane] = 0.0f;
    __syncthreads();

    constexpr int STEP = DIR ? -4 : 4;
    int gbase = DIR ? (TT - 4) : 0;
    float4 xq = *(const float4*)(base + gbase);

    for (int g = 0; g < TT / 4; ++g) {
        const int gnext = (g + 1 < TT / 4) ? (gbase + STEP) : gbase;
        const float4 xn = *(const float4*)(base + gnext);

        float hq0, hq1, hq2, hq3;
        if (DIR == 0) {
            RNN_STEP(xq.x, hq0, 0, 1)
            RNN_STEP(xq.y, hq1, 1, 0)
            RNN_STEP(xq.z, hq2, 0, 1)
            RNN_STEP(xq.w, hq3, 1, 0)
        } else {
            RNN_STEP(xq.w, hq0, 0, 1)
            RNN_STEP(xq.z, hq1, 1, 0)
            RNN_STEP(xq.y, hq2, 0, 1)
            RNN_STEP(xq.x, hq3, 1, 0)
        }

        float4 st;
        if (DIR == 0) { st.x = hq0; st.y = hq1; st.z = hq2; st.w = hq3; }
        else          { st.x = hq3; st.y = hq2; st.z = hq1; st.w = hq0; }
        *(float4*)(base + gbase) = st;

        gbase = gnext;
        xq = xn;
    }
}

// ---------------- rnn: identity fast-path (parallel scan) + fallback ----------
__global__ __launch_bounds__(64) void rnn_kernel(
    const float* __restrict__ Whf, const float* __restrict__ Whb,
    float* __restrict__ xh)
{
    const int lane = threadIdx.x;
    const int row  = blockIdx.x;         // 0..16383
    const int dir  = row >> 13;
    const int rid  = row & 8191;
    const int b    = rid >> 6;
    const int hrow = rid & 63;
    const float* W = dir ? Whb : Whf;

    bool ok = true;
    {
        const float4* wp = (const float4*)(W + lane * HH);
        #pragma unroll
        for (int j4 = 0; j4 < HH / 4; ++j4) {
            float4 v = wp[j4];
            ok &= (v.x == ((4*j4+0 == lane) ? 1.0f : 0.0f));
            ok &= (v.y == ((4*j4+1 == lane) ? 1.0f : 0.0f));
            ok &= (v.z == ((4*j4+2 == lane) ? 1.0f : 0.0f));
            ok &= (v.w == ((4*j4+3 == lane) ? 1.0f : 0.0f));
        }
    }
    const bool isI = (__ballot(ok) == ~0ull);

    if (!isI) {
        if (hrow != 0) return;
        if (dir == 0) rnn_serial<0>(Whf, xh, b, lane);
        else          rnn_serial<1>(Whb, xh, b, lane);
        return;
    }

    float* base = xh + ((size_t)(dir * BB + b) * HH + hrow) * TT;

    float a[32];
    if (dir == 0) {
        const float4* xp = (const float4*)(base + lane * 32);
        #pragma unroll
        for (int q = 0; q < 8; ++q) {
            float4 v = xp[q];
            a[4*q+0] = v.x; a[4*q+1] = v.y; a[4*q+2] = v.z; a[4*q+3] = v.w;
        }
    } else {
        const float4* xp = (const float4*)(base + (TT - 32 - lane * 32));
        #pragma unroll
        for (int q = 0; q < 8; ++q) {
            float4 v = xp[q];
            a[31-4*q] = v.x; a[30-4*q] = v.y; a[29-4*q] = v.z; a[28-4*q] = v.w;
        }
    }

    float A = 0.0f, Bv = -__builtin_inff();
    #pragma unroll
    for (int j = 0; j < 32; ++j) {
        A  = A + a[j];
        Bv = fmaxf(Bv + a[j], 0.0f);
    }

    #pragma unroll
    for (int off = 1; off < 64; off <<= 1) {
        float Au = __shfl_up(A,  (unsigned)off);
        float Bu = __shfl_up(Bv, (unsigned)off);
        if (lane >= off) {
            Bv = fmaxf(Bu + A, Bv);
            A  = Au + A;
        }
    }

    float Ae = __shfl_up(A, 1u);
    float Be = __shfl_up(Bv, 1u);
    float h = (lane == 0) ? 0.0f : fmaxf(Ae, Be);

    #pragma unroll
    for (int j = 0; j < 32; ++j) {
        h = fmaxf(h + a[j], 0.0f);
        a[j] = h;
    }

    if (dir == 0) {
        float4* op = (float4*)(base + lane * 32);
        #pragma unroll
        for (int q = 0; q < 8; ++q) {
            float4 st; st.x = a[4*q+0]; st.y = a[4*q+1]; st.z = a[4*q+2]; st.w = a[4*q+3];
            op[q] = st;
        }
    } else {
        float4* op = (float4*)(base + (TT - 32 - lane * 32));
        #pragma unroll
        for (int q = 0; q < 8; ++q) {
            float4 st; st.x = a[31-4*q]; st.y = a[30-4*q]; st.z = a[29-4*q]; st.w = a[28-4*q];
            op[q] = st;
        }
    }
}

// ---------------- mlp: h in LDS, 2 t per lane (32 named accs) ----------------
// R10 analysis: per jg a wave exposes the full s_load round-trip (~150 cyc)
// before 64 dependent FMAs (128 issue cyc) -> ~43% duty, VALUBusy 38%.
// A 2nd s_load bank in flight would blow the SGPR file (R8). So amortize the
// SAME bank over 2x FMAs: each lane handles t and t+64 (block covers 128 t,
// 64 KB LDS tile). 32 named accs (R7's 16 ok / R9's 64 spilled — midpoint).
// Per-t arithmetic order identical to R10 -> absmax must not move.
#define REP16(M) M(0) M(1) M(2) M(3) M(4) M(5) M(6) M(7) \
                 M(8) M(9) M(10) M(11) M(12) M(13) M(14) M(15)

__global__ __launch_bounds__(256, 2) void mlp_kernel(
    const float* __restrict__ xh,
    const float* __restrict__ w0, const float* __restrict__ b0,
    const float* __restrict__ w1, const float* __restrict__ b1,
    float* __restrict__ out)
{
    const int tid  = threadIdx.x;
    const int lane = tid & 63;
    const int wid  = __builtin_amdgcn_readfirstlane(tid >> 6); // 0..3
    const int blk  = blockIdx.x;          // 0..2047
    const int b    = blk >> 4;
    const int t0   = (blk & 15) << 7;     // 128 t per block

    __shared__ float hsh[2 * HH][128];    // 64 KB: [j][t]
    __shared__ float red[4][128];

    // cooperative load: 16384 floats; 512B contiguous per 128 threads
    {
        const float* pf = xh + (size_t)b * HH * TT + t0;
        const float* pb = xh + (size_t)(BB + b) * HH * TT + t0;
        #pragma unroll
        for (int it = 0; it < 64; ++it) {
            const int idx = it * 256 + tid;
            const int j = idx >> 7, tt = idx & 127;
            hsh[j][tt] = (j < HH) ? pf[(size_t)j * TT + tt]
                                  : pb[(size_t)(j - HH) * TT + tt];
        }
    }
    __syncthreads();

    float oaA = 0.0f, oaB = 0.0f;

    #pragma unroll 1
    for (int s = 0; s < 2; ++s) {
        const int kbase = wid * 32 + s * 16;
        const float* wk = w0 + (size_t)kbase * 128;    // wave-uniform -> s_loads

        #define DC(i) float cA##i = b0[kbase + i]; float cB##i = cA##i;
        REP16(DC)
        #undef DC

        #pragma unroll 1
        for (int jg = 0; jg < 32; ++jg) {
            const float hA = hsh[4*jg+0][lane];
            const float hB = hsh[4*jg+1][lane];
            const float hC = hsh[4*jg+2][lane];
            const float hD = hsh[4*jg+3][lane];
            const float gA = hsh[4*jg+0][64 + lane];
            const float gB = hsh[4*jg+1][64 + lane];
            const float gC = hsh[4*jg+2][64 + lane];
            const float gD = hsh[4*jg+3][64 + lane];
            #define WF(i) { float4 wq = *(const float4*)(wk + 4*jg + (i)*128); \
                            cA##i = fmaf(wq.x, hA, cA##i);                     \
                            cA##i = fmaf(wq.y, hB, cA##i);                     \
                            cA##i = fmaf(wq.z, hC, cA##i);                     \
                            cA##i = fmaf(wq.w, hD, cA##i);                     \
                            cB##i = fmaf(wq.x, gA, cB##i);                     \
                            cB##i = fmaf(wq.y, gB, cB##i);                     \
                            cB##i = fmaf(wq.z, gC, cB##i);                     \
                            cB##i = fmaf(wq.w, gD, cB##i); }
            REP16(WF)
            #undef WF
        }

        #define EP(i) { float v = fmaxf(cA##i, 0.01f * cA##i);  \
                        oaA = fmaf(v, w1[kbase + i], oaA);      \
                        float u = fmaxf(cB##i, 0.01f * cB##i);  \
                        oaB = fmaf(u, w1[kbase + i], oaB); }
        REP16(EP)
        #undef EP
    }

    red[wid][lane]      = oaA;
    red[wid][64 + lane] = oaB;
    __syncthreads();
    if (wid < 2) {
        const int tt = wid * 64 + lane;
        float r = ((red[0][tt] + red[1][tt]) + red[2][tt]) + red[3][tt];
        out[(size_t)b * TT + t0 + tt] = r + b1[0];
    }
}

extern "C" void kernel_launch(void* const* d_in, const int* in_sizes, int n_in,
                              void* d_out, int out_size, void* d_ws, size_t ws_size,
                              hipStream_t stream) {
    (void)in_sizes; (void)n_in; (void)out_size; (void)ws_size;
    const float* x    = (const float*)d_in[0];
    const float* Wihf = (const float*)d_in[1];
    const float* Whhf = (const float*)d_in[2];
    const float* bihf = (const float*)d_in[3];
    const float* bhhf = (const float*)d_in[4];
    const float* Wihb = (const float*)d_in[5];
    const float* Whhb = (const float*)d_in[6];
    const float* bihb = (const float*)d_in[7];
    const float* bhhb = (const float*)d_in[8];
    const float* ff0w = (const float*)d_in[9];
    const float* ff0b = (const float*)d_in[10];
    const float* ff1w = (const float*)d_in[11];
    const float* ff1b = (const float*)d_in[12];
    float* xh = (float*)d_ws;

    proj_kernel<<<dim3(BB * (TT / 64)), dim3(256), 0, stream>>>(
        x, Wihf, bihf, bhhf, Wihb, bihb, bhhb, xh);
    rnn_kernel<<<dim3(2 * BB * HH), dim3(64), 0, stream>>>(Whhf, Whhb, xh);
    mlp_kernel<<<dim3(BB * (TT / 128)), dim3(256), 0, stream>>>(
        xh, ff0w, ff0b, ff1w, ff1b, (float*)d_out);
}

// Round 12
// 293.582 us; speedup vs baseline: 2.0754x; 1.1208x over previous
//
#include <hip/hip_runtime.h>

#define BB 128
#define TT 2048
#define II 32
#define HH 64

// ws layout: float xh[2][BB][HH][TT]   (xw written by proj, overwritten in-place by h in rnn)
// total = 2*128*64*2048*4 = 128 MiB

__global__ __launch_bounds__(256) void proj_kernel(
    const float* __restrict__ x,
    const float* __restrict__ Wf, const float* __restrict__ bihf, const float* __restrict__ bhhf,
    const float* __restrict__ Wb, const float* __restrict__ bihb, const float* __restrict__ bhhb,
    float* __restrict__ xh)
{
    const int lane = threadIdx.x & 63;
    const int wv = __builtin_amdgcn_readfirstlane(threadIdx.x >> 6);
    const int blk = blockIdx.x;          // 0..4095
    const int b = blk >> 5;
    const int t = ((blk & 31) << 6) + lane;

    float xr[II];
    {
        const float4* xp = (const float4*)(x + ((size_t)b * TT + t) * II);
        #pragma unroll
        for (int k4 = 0; k4 < II / 4; ++k4) {
            float4 v = xp[k4];
            xr[4*k4+0] = v.x; xr[4*k4+1] = v.y; xr[4*k4+2] = v.z; xr[4*k4+3] = v.w;
        }
    }
    float* outF = xh + (size_t)b * HH * TT + t;
    float* outB = xh + (size_t)(BB + b) * HH * TT + t;
    #pragma unroll 4
    for (int ii = 0; ii < 16; ++ii) {
        const int i = wv * 16 + ii;                    // wave-uniform -> scalar W loads
        const float* wfr = Wf + i * II;
        const float* wbr = Wb + i * II;
        float af0 = bihf[i] + bhhf[i], af1 = 0.f;
        float ab0 = bihb[i] + bhhb[i], ab1 = 0.f;
        #pragma unroll
        for (int k = 0; k < II; k += 2) {
            af0 = fmaf(wfr[k],   xr[k],   af0);
            af1 = fmaf(wfr[k+1], xr[k+1], af1);
            ab0 = fmaf(wbr[k],   xr[k],   ab0);
            ab1 = fmaf(wbr[k+1], xr[k+1], ab1);
        }
        outF[(size_t)i * TT] = af0 + af1;   // coalesced 256B store
        outB[(size_t)i * TT] = ab0 + ab1;
    }
}

// ---------------- general-W fallback (serial chain), R2-proven ----------------
#define RNN_STEP(XOV, HQ, CURBUF, NXTBUF) {                                   \
    float a0 = (XOV), a1 = 0.f, a2 = 0.f, a3 = 0.f;                           \
    const float* hs = hsh[CURBUF];                                            \
    _Pragma("unroll")                                                         \
    for (int j4 = 0; j4 < HH / 4; ++j4) {                                     \
        float4 h4 = *(const float4*)(hs + 4 * j4);  /* ds_read_b128 bcast */  \
        a0 = fmaf(w[4*j4+0], h4.x, a0);                                       \
        a1 = fmaf(w[4*j4+1], h4.y, a1);                                       \
        a2 = fmaf(w[4*j4+2], h4.z, a2);                                       \
        a3 = fmaf(w[4*j4+3], h4.w, a3);                                       \
    }                                                                         \
    HQ = fmaxf((a0 + a1) + (a2 + a3), 0.0f);                                  \
    hsh[NXTBUF][lane] = HQ;                                                   \
}

template<int DIR>
__device__ __noinline__ void rnn_serial(const float* __restrict__ W,
                                        float* __restrict__ xh,
                                        int b, int lane)
{
    float w[HH];
    {
        const float4* wp = (const float4*)(W + lane * HH);
        #pragma unroll
        for (int j4 = 0; j4 < HH / 4; ++j4) {
            float4 v = wp[j4];
            w[4*j4+0] = v.x; w[4*j4+1] = v.y; w[4*j4+2] = v.z; w[4*j4+3] = v.w;
        }
    }
    float* base = xh + ((size_t)(DIR * BB + b) * HH + lane) * TT;

    __shared__ __align__(16) float hsh[2][HH];
    hsh[0][lane] = 0.0f;
    __syncthreads();

    constexpr int STEP = DIR ? -4 : 4;
    int gbase = DIR ? (TT - 4) : 0;
    float4 xq = *(const float4*)(base + gbase);

    for (int g = 0; g < TT / 4; ++g) {
        const int gnext = (g + 1 < TT / 4) ? (gbase + STEP) : gbase;
        const float4 xn = *(const float4*)(base + gnext);

        float hq0, hq1, hq2, hq3;
        if (DIR == 0) {
            RNN_STEP(xq.x, hq0, 0, 1)
            RNN_STEP(xq.y, hq1, 1, 0)
            RNN_STEP(xq.z, hq2, 0, 1)
            RNN_STEP(xq.w, hq3, 1, 0)
        } else {
            RNN_STEP(xq.w, hq0, 0, 1)
            RNN_STEP(xq.z, hq1, 1, 0)
            RNN_STEP(xq.y, hq2, 0, 1)
            RNN_STEP(xq.x, hq3, 1, 0)
        }

        float4 st;
        if (DIR == 0) { st.x = hq0; st.y = hq1; st.z = hq2; st.w = hq3; }
        else          { st.x = hq3; st.y = hq2; st.z = hq1; st.w = hq0; }
        *(float4*)(base + gbase) = st;

        gbase = gnext;
        xq = xn;
    }
}

// ---------------- rnn: identity fast-path (parallel scan) + fallback ----------
__global__ __launch_bounds__(64) void rnn_kernel(
    const float* __restrict__ Whf, const float* __restrict__ Whb,
    float* __restrict__ xh)
{
    const int lane = threadIdx.x;
    const int row  = blockIdx.x;         // 0..16383
    const int dir  = row >> 13;
    const int rid  = row & 8191;
    const int b    = rid >> 6;
    const int hrow = rid & 63;
    const float* W = dir ? Whb : Whf;

    bool ok = true;
    {
        const float4* wp = (const float4*)(W + lane * HH);
        #pragma unroll
        for (int j4 = 0; j4 < HH / 4; ++j4) {
            float4 v = wp[j4];
            ok &= (v.x == ((4*j4+0 == lane) ? 1.0f : 0.0f));
            ok &= (v.y == ((4*j4+1 == lane) ? 1.0f : 0.0f));
            ok &= (v.z == ((4*j4+2 == lane) ? 1.0f : 0.0f));
            ok &= (v.w == ((4*j4+3 == lane) ? 1.0f : 0.0f));
        }
    }
    const bool isI = (__ballot(ok) == ~0ull);

    if (!isI) {
        if (hrow != 0) return;
        if (dir == 0) rnn_serial<0>(Whf, xh, b, lane);
        else          rnn_serial<1>(Whb, xh, b, lane);
        return;
    }

    float* base = xh + ((size_t)(dir * BB + b) * HH + hrow) * TT;

    float a[32];
    if (dir == 0) {
        const float4* xp = (const float4*)(base + lane * 32);
        #pragma unroll
        for (int q = 0; q < 8; ++q) {
            float4 v = xp[q];
            a[4*q+0] = v.x; a[4*q+1] = v.y; a[4*q+2] = v.z; a[4*q+3] = v.w;
        }
    } else {
        const float4* xp = (const float4*)(base + (TT - 32 - lane * 32));
        #pragma unroll
        for (int q = 0; q < 8; ++q) {
            float4 v = xp[q];
            a[31-4*q] = v.x; a[30-4*q] = v.y; a[29-4*q] = v.z; a[28-4*q] = v.w;
        }
    }

    float A = 0.0f, Bv = -__builtin_inff();
    #pragma unroll
    for (int j = 0; j < 32; ++j) {
        A  = A + a[j];
        Bv = fmaxf(Bv + a[j], 0.0f);
    }

    #pragma unroll
    for (int off = 1; off < 64; off <<= 1) {
        float Au = __shfl_up(A,  (unsigned)off);
        float Bu = __shfl_up(Bv, (unsigned)off);
        if (lane >= off) {
            Bv = fmaxf(Bu + A, Bv);
            A  = Au + A;
        }
    }

    float Ae = __shfl_up(A, 1u);
    float Be = __shfl_up(Bv, 1u);
    float h = (lane == 0) ? 0.0f : fmaxf(Ae, Be);

    #pragma unroll
    for (int j = 0; j < 32; ++j) {
        h = fmaxf(h + a[j], 0.0f);
        a[j] = h;
    }

    if (dir == 0) {
        float4* op = (float4*)(base + lane * 32);
        #pragma unroll
        for (int q = 0; q < 8; ++q) {
            float4 st; st.x = a[4*q+0]; st.y = a[4*q+1]; st.z = a[4*q+2]; st.w = a[4*q+3];
            op[q] = st;
        }
    } else {
        float4* op = (float4*)(base + (TT - 32 - lane * 32));
        #pragma unroll
        for (int q = 0; q < 8; ++q) {
            float4 st; st.x = a[31-4*q]; st.y = a[30-4*q]; st.z = a[29-4*q]; st.w = a[28-4*q];
            op[q] = st;
        }
    }
}

// ---------------- mlp: 512-thr blocks, 8 waves, 2t/lane, 32 named accs -------
// R11 proved the wave body (16-s_load bank -> 32 accs -> 128 FMAs/jg; VGPR 88,
// no spill) but ran at 2 waves/SIMD (66 KB LDS, 256-thr blocks) -> VALUBusy
// 43%, latency holes unfillable. Same body, 512-thr blocks: 8 waves each own
// ONE 16-k quarter (no s loop) -> 2 blocks/CU = 4 waves/SIMD, double the TLP
// at identical per-wave cost. 8-way reduce in ascending-wid (=k) order.
#define REP16(M) M(0) M(1) M(2) M(3) M(4) M(5) M(6) M(7) \
                 M(8) M(9) M(10) M(11) M(12) M(13) M(14) M(15)

__global__ __launch_bounds__(512, 4) void mlp_kernel(
    const float* __restrict__ xh,
    const float* __restrict__ w0, const float* __restrict__ b0,
    const float* __restrict__ w1, const float* __restrict__ b1,
    float* __restrict__ out)
{
    const int tid  = threadIdx.x;
    const int lane = tid & 63;
    const int wid  = __builtin_amdgcn_readfirstlane(tid >> 6); // 0..7
    const int blk  = blockIdx.x;          // 0..2047
    const int b    = blk >> 4;
    const int t0   = (blk & 15) << 7;     // 128 t per block

    __shared__ float hsh[2 * HH][128];    // 64 KB: [j][t]
    __shared__ float red[8][128];         // 4 KB

    // cooperative load: 16384 floats; 2048B contiguous per 512 threads
    {
        const float* pf = xh + (size_t)b * HH * TT + t0;
        const float* pb = xh + (size_t)(BB + b) * HH * TT + t0;
        #pragma unroll
        for (int it = 0; it < 32; ++it) {
            const int idx = it * 512 + tid;
            const int j = idx >> 7, tt = idx & 127;
            hsh[j][tt] = (j < HH) ? pf[(size_t)j * TT + tt]
                                  : pb[(size_t)(j - HH) * TT + tt];
        }
    }
    __syncthreads();

    const int kbase = wid * 16;                    // this wave's k quarter
    const float* wk = w0 + (size_t)kbase * 128;    // wave-uniform -> s_loads

    #define DC(i) float cA##i = b0[kbase + i]; float cB##i = cA##i;
    REP16(DC)
    #undef DC

    #pragma unroll 1
    for (int jg = 0; jg < 32; ++jg) {
        const float hA = hsh[4*jg+0][lane];
        const float hB = hsh[4*jg+1][lane];
        const float hC = hsh[4*jg+2][lane];
        const float hD = hsh[4*jg+3][lane];
        const float gA = hsh[4*jg+0][64 + lane];
        const float gB = hsh[4*jg+1][64 + lane];
        const float gC = hsh[4*jg+2][64 + lane];
        const float gD = hsh[4*jg+3][64 + lane];
        #define WF(i) { float4 wq = *(const float4*)(wk + 4*jg + (i)*128); \
                        cA##i = fmaf(wq.x, hA, cA##i);                     \
                        cA##i = fmaf(wq.y, hB, cA##i);                     \
                        cA##i = fmaf(wq.z, hC, cA##i);                     \
                        cA##i = fmaf(wq.w, hD, cA##i);                     \
                        cB##i = fmaf(wq.x, gA, cB##i);                     \
                        cB##i = fmaf(wq.y, gB, cB##i);                     \
                        cB##i = fmaf(wq.z, gC, cB##i);                     \
                        cB##i = fmaf(wq.w, gD, cB##i); }
        REP16(WF)
        #undef WF
    }

    float oaA = 0.0f, oaB = 0.0f;
    #define EP(i) { float v = fmaxf(cA##i, 0.01f * cA##i);  \
                    oaA = fmaf(v, w1[kbase + i], oaA);      \
                    float u = fmaxf(cB##i, 0.01f * cB##i);  \
                    oaB = fmaf(u, w1[kbase + i], oaB); }
    REP16(EP)
    #undef EP

    red[wid][lane]      = oaA;
    red[wid][64 + lane] = oaB;
    __syncthreads();
    if (wid == 0) {
        float rA = red[0][lane];
        float rB = red[0][64 + lane];
        #pragma unroll
        for (int wv = 1; wv < 8; ++wv) {   // ascending wid = ascending k
            rA += red[wv][lane];
            rB += red[wv][64 + lane];
        }
        out[(size_t)b * TT + t0 + lane]      = rA + b1[0];
        out[(size_t)b * TT + t0 + 64 + lane] = rB + b1[0];
    }
}

extern "C" void kernel_launch(void* const* d_in, const int* in_sizes, int n_in,
                              void* d_out, int out_size, void* d_ws, size_t ws_size,
                              hipStream_t stream) {
    (void)in_sizes; (void)n_in; (void)out_size; (void)ws_size;
    const float* x    = (const float*)d_in[0];
    const float* Wihf = (const float*)d_in[1];
    const float* Whhf = (const float*)d_in[2];
    const float* bihf = (const float*)d_in[3];
    const float* bhhf = (const float*)d_in[4];
    const float* Wihb = (const float*)d_in[5];
    const float* Whhb = (const float*)d_in[6];
    const float* bihb = (const float*)d_in[7];
    const float* bhhb = (const float*)d_in[8];
    const float* ff0w = (const float*)d_in[9];
    const float* ff0b = (const float*)d_in[10];
    const float* ff1w = (const float*)d_in[11];
    const float* ff1b = (const float*)d_in[12];
    float* xh = (float*)d_ws;

    proj_kernel<<<dim3(BB * (TT / 64)), dim3(256), 0, stream>>>(
        x, Wihf, bihf, bhhf, Wihb, bihb, bhhb, xh);
    rnn_kernel<<<dim3(2 * BB * HH), dim3(64), 0, stream>>>(Whhf, Whhb, xh);
    mlp_kernel<<<dim3(BB * (TT / 128)), dim3(512), 0, stream>>>(
        xh, ff0w, ff0b, ff1w, ff1b, (float*)d_out);
}